// Round 8
// baseline (190.420 us; speedup 1.0000x reference)
//
#include <hip/hip_runtime.h>
#include <stdint.h>

#define GLOBAL_AS __attribute__((address_space(1)))
#define LDS_AS __attribute__((address_space(3)))

typedef _Float16 half_t;
typedef _Float16 f16x8 __attribute__((ext_vector_type(8)));
typedef float f32x4 __attribute__((ext_vector_type(4)));

static constexpr int BATCH = 8;
static constexpr int CH = 256;
static constexpr int N = 2304;     // 48*48
static constexpr int KTOT = 4096;  // 2 * BATCH * CH (G1 and G2 fused along K)
static constexpr int MW = 72;      // mask words per row (2304/32)
static constexpr int MWORDS = 165888;  // 2304*72
static constexpr int LROW = 258;   // LDS transpose row stride in halfs (odd word count)
static constexpr float EPS = 1e-8f;
static constexpr float THR = 31.5f;

// ws layout (nothing needs pre-zeroing; every slot written unconditionally):
//   s_part  = ws          : float [2592] per-gemm-block masked-sum partials
//   c_part  = ws + 10496  : uint  [864]  per-mask-block popcount partials
//   At = ws + 16384            : half [2304][4096] rows=n, k-contig ([yhat; zhat])
//   Bt = At + 18874368 B       : half [2304][4096] rows=m, k-contig ([zphat; yphat])
//   maskw = Bt + 18874368 B    : uint32 [2304][72] bitmask of (dist < THR)
// total ~36.6 MB

// ------------- 1. prep: fused norm+pack (z<4) and mask build (z>=4) -------------
__global__ __launch_bounds__(256) void prep_kernel(
    const float* __restrict__ y, const float* __restrict__ yp,
    const float* __restrict__ z, const float* __restrict__ zp,
    const float* __restrict__ dist,
    half_t* __restrict__ At, half_t* __restrict__ Bt,
    uint32_t* __restrict__ maskw, unsigned int* __restrict__ c_part) {
  const int t = threadIdx.x;
  const int bz = blockIdx.z;

  if (bz >= 4) {
    // ---- mask path: 3*8*36 = 864 blocks cover 165888 words ----
    const int blk = ((bz - 4) * 8 + blockIdx.y) * 36 + blockIdx.x;
    const int w = blk * 256 + t;
    int c = 0;
    if (w < MWORDS) {
      const float4* p = (const float4*)(dist + (size_t)w * 32);
      uint32_t bits = 0;
#pragma unroll
      for (int q = 0; q < 8; ++q) {
        float4 v = p[q];
        bits |= (v.x < THR ? 1u : 0u) << (q * 4);
        bits |= (v.y < THR ? 1u : 0u) << (q * 4 + 1);
        bits |= (v.z < THR ? 1u : 0u) << (q * 4 + 2);
        bits |= (v.w < THR ? 1u : 0u) << (q * 4 + 3);
      }
      maskw[w] = bits;
      c = __popc(bits);
    }
#pragma unroll
    for (int off = 32; off; off >>= 1) c += __shfl_down(c, off, 64);
    __shared__ int mred[4];
    if ((t & 63) == 0) mred[t >> 6] = c;
    __syncthreads();
    if (t == 0)
      c_part[blk] = (unsigned int)(mred[0] + mred[1] + mred[2] + mred[3]);
    return;
  }

  // ---- pack path: block = (tensor, batch, 64-n tile). Thread t owns 4 n's
  // ((t&15)*4+j) and one 16-channel k-chunk (cb=t>>4); 16 strided float4 loads
  // land its data k-contiguously in registers. Norms via small LDS reduce;
  // fp16 results staged through an LDS transpose tile so global stores are
  // 256-B contiguous runs (16 lanes x 16 B, same row).
  const int b = blockIdx.y;
  const int n0 = blockIdx.x * 64;  // 36*64 = 2304
  const float* src; half_t* dst; int kh;
  switch (bz) {
    case 0:  src = y;  dst = At; kh = 0;    break;
    case 1:  src = z;  dst = At; kh = 2048; break;
    case 2:  src = zp; dst = Bt; kh = 0;    break;
    default: src = yp; dst = Bt; kh = 2048; break;
  }
  const int kbase = kh + b * 256;
  const int col4 = (t & 15) * 4;   // n offset within tile
  const int cb = t >> 4;           // 16-channel k-chunk

  const float* base = src + (size_t)(b * CH + cb * 16) * N + n0 + col4;
  float4 v[16];
#pragma unroll
  for (int i = 0; i < 16; ++i) v[i] = *(const float4*)(base + (size_t)i * N);

  float ss[4] = {0.f, 0.f, 0.f, 0.f};
#pragma unroll
  for (int i = 0; i < 16; ++i) {
    ss[0] = fmaf(v[i].x, v[i].x, ss[0]);
    ss[1] = fmaf(v[i].y, v[i].y, ss[1]);
    ss[2] = fmaf(v[i].z, v[i].z, ss[2]);
    ss[3] = fmaf(v[i].w, v[i].w, ss[3]);
  }
  __shared__ float partial[16][65];
  __shared__ float sc[64];
  __shared__ half_t tile[64 * LROW];  // transpose staging, odd word row stride
#pragma unroll
  for (int j = 0; j < 4; ++j) partial[cb][col4 + j] = ss[j];
  __syncthreads();
  if (t < 64) {
    float s = 0.f;
#pragma unroll
    for (int k = 0; k < 16; ++k) s += partial[k][t];
    sc[t] = 1.0f / fmaxf(sqrtf(s), EPS);
  }
  __syncthreads();

  // normalize -> fp16 -> LDS transpose tile
#pragma unroll
  for (int j = 0; j < 4; ++j) {
    const float scj = sc[col4 + j];
    union { half_t h[16]; f16x8 v2[2]; } u;
#pragma unroll
    for (int i = 0; i < 16; ++i)
      u.h[i] = (half_t)(((const float*)&v[i])[j] * scj);
    f16x8* q = (f16x8*)(tile + (col4 + j) * LROW + cb * 16);
    q[0] = u.v2[0];
    q[1] = u.v2[1];
  }
  __syncthreads();

  // write-out: thread (r = t>>4, c = t&15); 4 row-passes x 2 instr;
  // each instruction: 16 lanes x 16 B contiguous in one row (256-B runs).
  {
    const int r = t >> 4, c = t & 15;
#pragma unroll
    for (int p = 0; p < 4; ++p) {
      const int row = p * 16 + r;
      half_t* gout = dst + (size_t)(n0 + row) * KTOT + kbase;
      const half_t* lrow = tile + row * LROW;
#pragma unroll
      for (int inst = 0; inst < 2; ++inst) {
        const int off = c * 8 + inst * 128;
        *(f16x8*)(gout + off) = *(const f16x8*)(lrow + off);
      }
    }
  }
}

// ---------------- 2. GEMM s_part[bid] = sum_mask (At * Bt^T) tile ----------------
// 128x128 tile, BK=32, K-split z=8 (2592 blocks, 1-D grid, ~10 blocks/CU for
// finer residency rotation; traffic made cheap by the XCD map below).
// XCD-aware brick mapping (bi&7 -> XCD, HW-confirmed in R7: FETCH 129->39 MB):
// each XCD owns one z-slice; v=bi>>3 walks mt inner so the 18 B-panels
// (2.3 MB at K=512) stay L2-resident while A-panels stream once each.
// LDS XOR-swizzled: slot (row, c') holds global chunk c' ^ ((row>>1)&3)
// -> all LDS ops 2-way (free, SQ_LDS_BANK_CONFLICT = 0).
__global__ __launch_bounds__(256) void gemm_kernel(
    const half_t* __restrict__ At, const half_t* __restrict__ Bt,
    const uint32_t* __restrict__ maskw, float* __restrict__ s_part) {
  __shared__ half_t As[128 * 32];
  __shared__ half_t Bs[128 * 32];
  __shared__ float red[4];

  const int t = threadIdx.x;
  const int lane = t & 63;
  const int w = t >> 6;

  const int bi = blockIdx.x;        // [0,2592)
  const int zt = bi & 7;            // XCD slot = K-split slice
  const int v  = bi >> 3;           // [0,324) within-XCD order
  const int nt = v / 18;            // outer: A-panel (n) changes slowly
  const int mt = v % 18;            // inner: B-panels cycle, L2-resident
  const int m0 = mt * 128;
  const int n0 = nt * 128;
  const int k0 = zt * 512;

  const int srow = w * 16 + (lane >> 2);
  const int schunk = ((lane & 3) ^ ((lane >> 3) & 3)) * 8;  // halfs
  const half_t* gA = At + (size_t)(n0 + srow) * KTOT + k0 + schunk;
  const half_t* gB = Bt + (size_t)(m0 + srow) * KTOT + k0 + schunk;
  half_t* lA = As + (size_t)(w * 16) * 32;  // wave-uniform LDS base
  half_t* lB = Bs + (size_t)(w * 16) * 32;

  const int wm = (w & 1) * 64;   // n-dim wave offset
  const int wn = (w >> 1) * 64;  // m-dim wave offset
  const int fra = wm + (lane & 15);
  const int frb = wn + (lane & 15);
  const int fk = ((lane >> 4) ^ ((lane >> 1) & 3)) * 8;

  f32x4 acc[4][4] = {};

  for (int kt = 0; kt < 16; ++kt) {
    const half_t* ga = gA + kt * 32;
    const half_t* gb = gB + kt * 32;
    __builtin_amdgcn_global_load_lds((const GLOBAL_AS void*)ga,               (LDS_AS void*)lA,             16, 0, 0);
    __builtin_amdgcn_global_load_lds((const GLOBAL_AS void*)(ga + 64 * KTOT), (LDS_AS void*)(lA + 64 * 32), 16, 0, 0);
    __builtin_amdgcn_global_load_lds((const GLOBAL_AS void*)gb,               (LDS_AS void*)lB,             16, 0, 0);
    __builtin_amdgcn_global_load_lds((const GLOBAL_AS void*)(gb + 64 * KTOT), (LDS_AS void*)(lB + 64 * 32), 16, 0, 0);
    __syncthreads();
    f16x8 af[4], bf[4];
#pragma unroll
    for (int i = 0; i < 4; ++i) af[i] = *(const f16x8*)(As + (fra + i * 16) * 32 + fk);
#pragma unroll
    for (int j = 0; j < 4; ++j) bf[j] = *(const f16x8*)(Bs + (frb + j * 16) * 32 + fk);
#pragma unroll
    for (int i = 0; i < 4; ++i)
#pragma unroll
      for (int j = 0; j < 4; ++j)
        acc[i][j] = __builtin_amdgcn_mfma_f32_16x16x32_f16(af[i], bf[j], acc[i][j], 0, 0, 0);
    __syncthreads();
  }

  // masked-sum epilogue via bitmask; C/D: col = lane&15 (m), row = (lane>>4)*4+reg (n)
  float local = 0.f;
  const int mbase = (m0 + wn) >> 5;
  const int mbit = lane & 15;
#pragma unroll
  for (int i = 0; i < 4; ++i) {
    const int ng = n0 + wm + i * 16 + (lane >> 4) * 4;
#pragma unroll
    for (int r = 0; r < 4; ++r) {
      const uint32_t* rw = maskw + (size_t)(ng + r) * MW + mbase;
      const uint32_t w0 = rw[0], w1 = rw[1];
      if ((w0 >> mbit) & 1u)        local += acc[i][0][r];
      if ((w0 >> (mbit + 16)) & 1u) local += acc[i][1][r];
      if ((w1 >> mbit) & 1u)        local += acc[i][2][r];
      if ((w1 >> (mbit + 16)) & 1u) local += acc[i][3][r];
    }
  }
#pragma unroll
  for (int off = 32; off; off >>= 1) local += __shfl_down(local, off, 64);
  if (lane == 0) red[w] = local;
  __syncthreads();
  if (t == 0) s_part[bi] = red[0] + red[1] + red[2] + red[3];
}

// ------- 3. finalize: reduce 2592 s-partials + 864 count-partials -------
__global__ void finalize_kernel(const float* __restrict__ s_part,
                                const unsigned int* __restrict__ c_part,
                                float* __restrict__ out) {
  const int t = threadIdx.x;
  float local = 0.f;
  for (int i = t; i < 2592; i += 256) local += s_part[i];
  unsigned int clocal = 0;
  for (int i = t; i < 864; i += 256) clocal += c_part[i];
#pragma unroll
  for (int off = 32; off; off >>= 1) {
    local += __shfl_down(local, off, 64);
    clocal += __shfl_down(clocal, off, 64);
  }
  __shared__ float red[4];
  __shared__ unsigned int credu[4];
  if ((t & 63) == 0) { red[t >> 6] = local; credu[t >> 6] = clocal; }
  __syncthreads();
  if (t == 0) {
    const float s = red[0] + red[1] + red[2] + red[3];
    const float cnt = (float)(credu[0] + credu[1] + credu[2] + credu[3]);
    out[0] = -s / (cnt * (float)BATCH);
  }
}

extern "C" void kernel_launch(void* const* d_in, const int* in_sizes, int n_in,
                              void* d_out, int out_size, void* d_ws, size_t ws_size,
                              hipStream_t stream) {
  const float* y    = (const float*)d_in[0];
  const float* yp   = (const float*)d_in[1];
  const float* z    = (const float*)d_in[2];
  const float* zp   = (const float*)d_in[3];
  const float* dist = (const float*)d_in[4];
  float* out = (float*)d_out;

  char* ws = (char*)d_ws;
  float* s_part = (float*)ws;
  unsigned int* c_part = (unsigned int*)(ws + 10496);
  half_t* At = (half_t*)(ws + 16384);
  half_t* Bt = (half_t*)(ws + 16384 + 18874368);
  uint32_t* maskw = (uint32_t*)(ws + 16384 + 2 * 18874368);

  prep_kernel<<<dim3(36, 8, 7), 256, 0, stream>>>(y, yp, z, zp, dist, At, Bt, maskw, c_part);
  gemm_kernel<<<dim3(2592), 256, 0, stream>>>(At, Bt, maskw, s_part);
  finalize_kernel<<<1, 256, 0, stream>>>(s_part, c_part, out);
}

// Round 9
// 188.825 us; speedup vs baseline: 1.0084x; 1.0084x over previous
//
#include <hip/hip_runtime.h>
#include <stdint.h>

#define GLOBAL_AS __attribute__((address_space(1)))
#define LDS_AS __attribute__((address_space(3)))

typedef _Float16 half_t;
typedef _Float16 f16x8 __attribute__((ext_vector_type(8)));
typedef float f32x4 __attribute__((ext_vector_type(4)));

static constexpr int BATCH = 8;
static constexpr int CH = 256;
static constexpr int N = 2304;     // 48*48
static constexpr int KTOT = 4096;  // 2 * BATCH * CH (G1 and G2 fused along K)
static constexpr int MW = 72;      // mask words per row (2304/32)
static constexpr int MWORDS = 165888;  // 2304*72
static constexpr int LROW = 258;   // LDS transpose row stride in halfs (odd word count)
static constexpr float EPS = 1e-8f;
static constexpr float THR = 31.5f;

// ws layout (nothing needs pre-zeroing; every slot written unconditionally):
//   s_part  = ws         : float [1296] per-gemm-block masked-sum partials
//   c_part  = ws + 8192  : uint  [864]  per-mask-block popcount partials
//   At = ws + 16384            : half [2304][4096] rows=n, k-contig ([yhat; zhat])
//   Bt = At + 18874368 B       : half [2304][4096] rows=m, k-contig ([zphat; yphat])
//   maskw = Bt + 18874368 B    : uint32 [2304][72] bitmask of (dist < THR)
// total ~36.6 MB

// ------------- 1. prep: fused norm+pack (z<4) and mask build (z>=4) -------------
__global__ __launch_bounds__(256) void prep_kernel(
    const float* __restrict__ y, const float* __restrict__ yp,
    const float* __restrict__ z, const float* __restrict__ zp,
    const float* __restrict__ dist,
    half_t* __restrict__ At, half_t* __restrict__ Bt,
    uint32_t* __restrict__ maskw, unsigned int* __restrict__ c_part) {
  const int t = threadIdx.x;
  const int bz = blockIdx.z;

  if (bz >= 4) {
    // ---- mask path: 3*8*36 = 864 blocks cover 165888 words ----
    const int blk = ((bz - 4) * 8 + blockIdx.y) * 36 + blockIdx.x;
    const int w = blk * 256 + t;
    int c = 0;
    if (w < MWORDS) {
      const float4* p = (const float4*)(dist + (size_t)w * 32);
      uint32_t bits = 0;
#pragma unroll
      for (int q = 0; q < 8; ++q) {
        float4 v = p[q];
        bits |= (v.x < THR ? 1u : 0u) << (q * 4);
        bits |= (v.y < THR ? 1u : 0u) << (q * 4 + 1);
        bits |= (v.z < THR ? 1u : 0u) << (q * 4 + 2);
        bits |= (v.w < THR ? 1u : 0u) << (q * 4 + 3);
      }
      maskw[w] = bits;
      c = __popc(bits);
    }
#pragma unroll
    for (int off = 32; off; off >>= 1) c += __shfl_down(c, off, 64);
    __shared__ int mred[4];
    if ((t & 63) == 0) mred[t >> 6] = c;
    __syncthreads();
    if (t == 0)
      c_part[blk] = (unsigned int)(mred[0] + mred[1] + mred[2] + mred[3]);
    return;
  }

  // ---- pack path: block = (tensor, batch, 64-n tile). Thread t owns 4 n's
  // ((t&15)*4+j) and one 16-channel k-chunk (cb=t>>4); 16 strided float4 loads
  // land its data k-contiguously in registers. Norms via small LDS reduce;
  // fp16 results staged through an LDS transpose tile so global stores are
  // 256-B contiguous runs (16 lanes x 16 B, same row).
  const int b = blockIdx.y;
  const int n0 = blockIdx.x * 64;  // 36*64 = 2304
  const float* src; half_t* dst; int kh;
  switch (bz) {
    case 0:  src = y;  dst = At; kh = 0;    break;
    case 1:  src = z;  dst = At; kh = 2048; break;
    case 2:  src = zp; dst = Bt; kh = 0;    break;
    default: src = yp; dst = Bt; kh = 2048; break;
  }
  const int kbase = kh + b * 256;
  const int col4 = (t & 15) * 4;   // n offset within tile
  const int cb = t >> 4;           // 16-channel k-chunk

  const float* base = src + (size_t)(b * CH + cb * 16) * N + n0 + col4;
  float4 v[16];
#pragma unroll
  for (int i = 0; i < 16; ++i) v[i] = *(const float4*)(base + (size_t)i * N);

  float ss[4] = {0.f, 0.f, 0.f, 0.f};
#pragma unroll
  for (int i = 0; i < 16; ++i) {
    ss[0] = fmaf(v[i].x, v[i].x, ss[0]);
    ss[1] = fmaf(v[i].y, v[i].y, ss[1]);
    ss[2] = fmaf(v[i].z, v[i].z, ss[2]);
    ss[3] = fmaf(v[i].w, v[i].w, ss[3]);
  }
  __shared__ float partial[16][65];
  __shared__ float sc[64];
  __shared__ half_t tile[64 * LROW];  // transpose staging, odd word row stride
#pragma unroll
  for (int j = 0; j < 4; ++j) partial[cb][col4 + j] = ss[j];
  __syncthreads();
  if (t < 64) {
    float s = 0.f;
#pragma unroll
    for (int k = 0; k < 16; ++k) s += partial[k][t];
    sc[t] = 1.0f / fmaxf(sqrtf(s), EPS);
  }
  __syncthreads();

  // normalize -> fp16 -> LDS transpose tile
#pragma unroll
  for (int j = 0; j < 4; ++j) {
    const float scj = sc[col4 + j];
    union { half_t h[16]; f16x8 v2[2]; } u;
#pragma unroll
    for (int i = 0; i < 16; ++i)
      u.h[i] = (half_t)(((const float*)&v[i])[j] * scj);
    f16x8* q = (f16x8*)(tile + (col4 + j) * LROW + cb * 16);
    q[0] = u.v2[0];
    q[1] = u.v2[1];
  }
  __syncthreads();

  // write-out: thread (r = t>>4, c = t&15); 4 row-passes x 2 instr;
  // each instruction: 16 lanes x 16 B contiguous in one row (256-B runs).
  {
    const int r = t >> 4, c = t & 15;
#pragma unroll
    for (int p = 0; p < 4; ++p) {
      const int row = p * 16 + r;
      half_t* gout = dst + (size_t)(n0 + row) * KTOT + kbase;
      const half_t* lrow = tile + row * LROW;
#pragma unroll
      for (int inst = 0; inst < 2; ++inst) {
        const int off = c * 8 + inst * 128;
        *(f16x8*)(gout + off) = *(const f16x8*)(lrow + off);
      }
    }
  }
}

// ---------------- 2. GEMM s_part[bid] = sum_mask (At * Bt^T) tile ----------------
// 256(m)x128(n) tile, BK=32, z=8 (162 tiles x 8 = 1296 blocks). Bigger tile
// cuts L2->LDS staging from 663 MB (128x128) to 510 MB — R8 showed the gemm
// pinned at ~42 B/cyc/CU of LDS-staging traffic regardless of FETCH/z.
// 4 waves: wave w owns m in [wn, wn+128), n in [wm, wm+64); acc[4][8].
// XCD brick map (bi&7 -> XCD, HW-confirmed R7): per XCD one z-slice, mt inner
// so its 9 B-panels (2.4 MB at K=512) stay L2-resident.
// LDS XOR-swizzle as before: slot (row,c') holds chunk c'^((row>>1)&3).
__global__ __launch_bounds__(256, 2) void gemm_kernel(
    const half_t* __restrict__ At, const half_t* __restrict__ Bt,
    const uint32_t* __restrict__ maskw, float* __restrict__ s_part) {
  __shared__ half_t As[128 * 32];
  __shared__ half_t Bs[256 * 32];
  __shared__ float red[4];

  const int t = threadIdx.x;
  const int lane = t & 63;
  const int w = t >> 6;

  const int bi = blockIdx.x;        // [0,1296)
  const int zt = bi & 7;            // XCD slot = K-split slice
  const int v  = bi >> 3;           // [0,162) within-XCD order
  const int nt = v / 9;             // outer: A-panel changes slowly
  const int mt = v % 9;             // inner: B-panels cycle, L2-resident
  const int m0 = mt * 256;
  const int n0 = nt * 128;
  const int k0 = zt * 512;

  const int srlane = lane >> 2;     // row within 16-row group
  const int schunk = ((lane & 3) ^ ((lane >> 3) & 3)) * 8;  // halfs
  const half_t* gA = At + (size_t)(n0 + w * 32 + srlane) * KTOT + k0 + schunk;
  const half_t* gB = Bt + (size_t)(m0 + w * 64 + srlane) * KTOT + k0 + schunk;
  half_t* lA = As + (w * 32) * 32;  // wave-uniform LDS bases
  half_t* lB = Bs + (w * 64) * 32;

  const int wm = (w & 1) * 64;    // n-dim wave offset
  const int wn = (w >> 1) * 128;  // m-dim wave offset
  const int fra = wm + (lane & 15);
  const int frb = wn + (lane & 15);
  const int fk = ((lane >> 4) ^ ((lane >> 1) & 3)) * 8;

  f32x4 acc[4][8] = {};

  for (int kt = 0; kt < 16; ++kt) {
    const half_t* ga = gA + kt * 32;
    const half_t* gb = gB + kt * 32;
    __builtin_amdgcn_global_load_lds((const GLOBAL_AS void*)ga,               (LDS_AS void*)lA,             16, 0, 0);
    __builtin_amdgcn_global_load_lds((const GLOBAL_AS void*)(ga + 16 * KTOT), (LDS_AS void*)(lA + 16 * 32), 16, 0, 0);
    __builtin_amdgcn_global_load_lds((const GLOBAL_AS void*)gb,               (LDS_AS void*)lB,             16, 0, 0);
    __builtin_amdgcn_global_load_lds((const GLOBAL_AS void*)(gb + 16 * KTOT), (LDS_AS void*)(lB + 16 * 32), 16, 0, 0);
    __builtin_amdgcn_global_load_lds((const GLOBAL_AS void*)(gb + 32 * KTOT), (LDS_AS void*)(lB + 32 * 32), 16, 0, 0);
    __builtin_amdgcn_global_load_lds((const GLOBAL_AS void*)(gb + 48 * KTOT), (LDS_AS void*)(lB + 48 * 32), 16, 0, 0);
    __syncthreads();
    f16x8 af[4], bf[8];
#pragma unroll
    for (int i = 0; i < 4; ++i) af[i] = *(const f16x8*)(As + (fra + i * 16) * 32 + fk);
#pragma unroll
    for (int j = 0; j < 8; ++j) bf[j] = *(const f16x8*)(Bs + (frb + j * 16) * 32 + fk);
#pragma unroll
    for (int i = 0; i < 4; ++i)
#pragma unroll
      for (int j = 0; j < 8; ++j)
        acc[i][j] = __builtin_amdgcn_mfma_f32_16x16x32_f16(af[i], bf[j], acc[i][j], 0, 0, 0);
    __syncthreads();
  }

  // masked-sum epilogue; C/D: col = lane&15 (m), row = (lane>>4)*4+reg (n).
  // j spans 128 m -> 4 mask words, read as one aligned uint4.
  float local = 0.f;
  const int mbase = (m0 + wn) >> 5;  // multiple of 4 -> uint4-aligned
  const int mbit = lane & 15;
#pragma unroll
  for (int i = 0; i < 4; ++i) {
    const int ng = n0 + wm + i * 16 + (lane >> 4) * 4;
#pragma unroll
    for (int r = 0; r < 4; ++r) {
      const uint4 wv = *(const uint4*)(maskw + (size_t)(ng + r) * MW + mbase);
      const uint32_t ww[4] = {wv.x, wv.y, wv.z, wv.w};
#pragma unroll
      for (int jp = 0; jp < 4; ++jp) {
        if ((ww[jp] >> mbit) & 1u)        local += acc[i][2 * jp][r];
        if ((ww[jp] >> (mbit + 16)) & 1u) local += acc[i][2 * jp + 1][r];
      }
    }
  }
#pragma unroll
  for (int off = 32; off; off >>= 1) local += __shfl_down(local, off, 64);
  if (lane == 0) red[w] = local;
  __syncthreads();
  if (t == 0) s_part[bi] = red[0] + red[1] + red[2] + red[3];
}

// ------- 3. finalize: reduce 1296 s-partials + 864 count-partials -------
__global__ void finalize_kernel(const float* __restrict__ s_part,
                                const unsigned int* __restrict__ c_part,
                                float* __restrict__ out) {
  const int t = threadIdx.x;
  float local = 0.f;
  for (int i = t; i < 1296; i += 256) local += s_part[i];
  unsigned int clocal = 0;
  for (int i = t; i < 864; i += 256) clocal += c_part[i];
#pragma unroll
  for (int off = 32; off; off >>= 1) {
    local += __shfl_down(local, off, 64);
    clocal += __shfl_down(clocal, off, 64);
  }
  __shared__ float red[4];
  __shared__ unsigned int credu[4];
  if ((t & 63) == 0) { red[t >> 6] = local; credu[t >> 6] = clocal; }
  __syncthreads();
  if (t == 0) {
    const float s = red[0] + red[1] + red[2] + red[3];
    const float cnt = (float)(credu[0] + credu[1] + credu[2] + credu[3]);
    out[0] = -s / (cnt * (float)BATCH);
  }
}

extern "C" void kernel_launch(void* const* d_in, const int* in_sizes, int n_in,
                              void* d_out, int out_size, void* d_ws, size_t ws_size,
                              hipStream_t stream) {
  const float* y    = (const float*)d_in[0];
  const float* yp   = (const float*)d_in[1];
  const float* z    = (const float*)d_in[2];
  const float* zp   = (const float*)d_in[3];
  const float* dist = (const float*)d_in[4];
  float* out = (float*)d_out;

  char* ws = (char*)d_ws;
  float* s_part = (float*)ws;
  unsigned int* c_part = (unsigned int*)(ws + 8192);
  half_t* At = (half_t*)(ws + 16384);
  half_t* Bt = (half_t*)(ws + 16384 + 18874368);
  uint32_t* maskw = (uint32_t*)(ws + 16384 + 2 * 18874368);

  prep_kernel<<<dim3(36, 8, 7), 256, 0, stream>>>(y, yp, z, zp, dist, At, Bt, maskw, c_part);
  gemm_kernel<<<dim3(1296), 256, 0, stream>>>(At, Bt, maskw, s_part);
  finalize_kernel<<<1, 256, 0, stream>>>(s_part, c_part, out);
}

// Round 10
// 179.686 us; speedup vs baseline: 1.0597x; 1.0509x over previous
//
#include <hip/hip_runtime.h>
#include <stdint.h>

#define GLOBAL_AS __attribute__((address_space(1)))
#define LDS_AS __attribute__((address_space(3)))

typedef _Float16 half_t;
typedef _Float16 f16x8 __attribute__((ext_vector_type(8)));
typedef float f32x4 __attribute__((ext_vector_type(4)));

static constexpr int BATCH = 8;
static constexpr int CH = 256;
static constexpr int N = 2304;     // 48*48
static constexpr int KTOT = 4096;  // 2 * BATCH * CH (G1 and G2 fused along K)
static constexpr int MW = 72;      // mask words per row (2304/32)
static constexpr int MWORDS = 165888;  // 2304*72
static constexpr int LROW = 258;   // LDS transpose row stride in halfs (odd word count)
static constexpr float EPS = 1e-8f;
static constexpr float THR = 31.5f;

// ws layout (nothing needs pre-zeroing; every slot written unconditionally):
//   s_part  = ws         : float [1296] per-gemm-block masked-sum partials
//   c_part  = ws + 8192  : uint  [864]  per-mask-block popcount partials
//   At = ws + 16384            : half [2304][4096] rows=n, k-contig ([yhat; zhat])
//   Bt = At + 18874368 B       : half [2304][4096] rows=m, k-contig ([zphat; yphat])
//   maskw = Bt + 18874368 B    : uint32 [2304][72] bitmask of (dist < THR)
// total ~36.6 MB

// ------------- 1. prep: fused norm+pack (z<4) and mask build (z>=4) -------------
__global__ __launch_bounds__(256) void prep_kernel(
    const float* __restrict__ y, const float* __restrict__ yp,
    const float* __restrict__ z, const float* __restrict__ zp,
    const float* __restrict__ dist,
    half_t* __restrict__ At, half_t* __restrict__ Bt,
    uint32_t* __restrict__ maskw, unsigned int* __restrict__ c_part) {
  const int t = threadIdx.x;
  const int bz = blockIdx.z;

  if (bz >= 4) {
    // ---- mask path: 3*8*36 = 864 blocks cover 165888 words ----
    const int blk = ((bz - 4) * 8 + blockIdx.y) * 36 + blockIdx.x;
    const int w = blk * 256 + t;
    int c = 0;
    if (w < MWORDS) {
      const float4* p = (const float4*)(dist + (size_t)w * 32);
      uint32_t bits = 0;
#pragma unroll
      for (int q = 0; q < 8; ++q) {
        float4 v = p[q];
        bits |= (v.x < THR ? 1u : 0u) << (q * 4);
        bits |= (v.y < THR ? 1u : 0u) << (q * 4 + 1);
        bits |= (v.z < THR ? 1u : 0u) << (q * 4 + 2);
        bits |= (v.w < THR ? 1u : 0u) << (q * 4 + 3);
      }
      maskw[w] = bits;
      c = __popc(bits);
    }
#pragma unroll
    for (int off = 32; off; off >>= 1) c += __shfl_down(c, off, 64);
    __shared__ int mred[4];
    if ((t & 63) == 0) mred[t >> 6] = c;
    __syncthreads();
    if (t == 0)
      c_part[blk] = (unsigned int)(mred[0] + mred[1] + mred[2] + mred[3]);
    return;
  }

  // ---- pack path: block = (tensor, batch, 64-n tile). Thread t owns 4 n's
  // ((t&15)*4+j) and one 16-channel k-chunk (cb=t>>4); 16 strided float4 loads
  // land its data k-contiguously in registers. Norms via small LDS reduce;
  // fp16 results staged through an LDS transpose tile so global stores are
  // 256-B contiguous runs (16 lanes x 16 B, same row).
  const int b = blockIdx.y;
  const int n0 = blockIdx.x * 64;  // 36*64 = 2304
  const float* src; half_t* dst; int kh;
  switch (bz) {
    case 0:  src = y;  dst = At; kh = 0;    break;
    case 1:  src = z;  dst = At; kh = 2048; break;
    case 2:  src = zp; dst = Bt; kh = 0;    break;
    default: src = yp; dst = Bt; kh = 2048; break;
  }
  const int kbase = kh + b * 256;
  const int col4 = (t & 15) * 4;   // n offset within tile
  const int cb = t >> 4;           // 16-channel k-chunk

  const float* base = src + (size_t)(b * CH + cb * 16) * N + n0 + col4;
  float4 v[16];
#pragma unroll
  for (int i = 0; i < 16; ++i) v[i] = *(const float4*)(base + (size_t)i * N);

  float ss[4] = {0.f, 0.f, 0.f, 0.f};
#pragma unroll
  for (int i = 0; i < 16; ++i) {
    ss[0] = fmaf(v[i].x, v[i].x, ss[0]);
    ss[1] = fmaf(v[i].y, v[i].y, ss[1]);
    ss[2] = fmaf(v[i].z, v[i].z, ss[2]);
    ss[3] = fmaf(v[i].w, v[i].w, ss[3]);
  }
  __shared__ float partial[16][65];
  __shared__ float sc[64];
  __shared__ half_t tile[64 * LROW];  // transpose staging, odd word row stride
#pragma unroll
  for (int j = 0; j < 4; ++j) partial[cb][col4 + j] = ss[j];
  __syncthreads();
  if (t < 64) {
    float s = 0.f;
#pragma unroll
    for (int k = 0; k < 16; ++k) s += partial[k][t];
    sc[t] = 1.0f / fmaxf(sqrtf(s), EPS);
  }
  __syncthreads();

  // normalize -> fp16 -> LDS transpose tile
#pragma unroll
  for (int j = 0; j < 4; ++j) {
    const float scj = sc[col4 + j];
    union { half_t h[16]; f16x8 v2[2]; } u;
#pragma unroll
    for (int i = 0; i < 16; ++i)
      u.h[i] = (half_t)(((const float*)&v[i])[j] * scj);
    f16x8* q = (f16x8*)(tile + (col4 + j) * LROW + cb * 16);
    q[0] = u.v2[0];
    q[1] = u.v2[1];
  }
  __syncthreads();

  // write-out: thread (r = t>>4, c = t&15); 4 row-passes x 2 instr;
  // each instruction: 16 lanes x 16 B contiguous in one row (256-B runs).
  {
    const int r = t >> 4, c = t & 15;
#pragma unroll
    for (int p = 0; p < 4; ++p) {
      const int row = p * 16 + r;
      half_t* gout = dst + (size_t)(n0 + row) * KTOT + kbase;
      const half_t* lrow = tile + row * LROW;
#pragma unroll
      for (int inst = 0; inst < 2; ++inst) {
        const int off = c * 8 + inst * 128;
        *(f16x8*)(gout + off) = *(const f16x8*)(lrow + off);
      }
    }
  }
}

// ---------------- 2. GEMM s_part[bid] = sum_mask (At * Bt^T) tile ----------------
// 256(m)x128(n) tile, BK=64 (8 barrier-regions instead of 16 — R9 showed all
// pipes <45% busy; the residual cost is the per-region vmcnt(0)+barrier drain,
// so halve the region count at constant staging volume/FLOP).
// 4 waves: wave w owns m in [wn,wn+128), n in [wm,wm+64); acc[4][8].
// XCD brick map (bi&7 -> XCD, HW-confirmed R7): per XCD one z-slice, mt inner
// so its 9 B-panels stay L2-resident (FETCH ~21 MB measured).
// LDS XOR-swizzle for 8-chunk (128 B) rows: slot(row,c') holds global chunk
// c' ^ (row&7); frag reads hit 8 distinct 4-bank groups x 2 lanes = 2-way (free).
__global__ __launch_bounds__(256, 2) void gemm_kernel(
    const half_t* __restrict__ At, const half_t* __restrict__ Bt,
    const uint32_t* __restrict__ maskw, float* __restrict__ s_part) {
  __shared__ half_t As[128 * 64];
  __shared__ half_t Bs[256 * 64];
  __shared__ float red[4];

  const int t = threadIdx.x;
  const int lane = t & 63;
  const int w = t >> 6;

  const int bi = blockIdx.x;        // [0,1296)
  const int zt = bi & 7;            // XCD slot = K-split slice
  const int v  = bi >> 3;           // [0,162) within-XCD order
  const int nt = v / 9;             // outer: A-panel changes slowly
  const int mt = v % 9;             // inner: B-panels cycle, L2-resident
  const int m0 = mt * 256;
  const int n0 = nt * 128;
  const int k0 = zt * 512;

  // staging: one instr = 8 rows x 8 chunks (64 lanes); lane -> row lane>>3,
  // LDS slot lane&7; fetch global chunk (lane&7) ^ ((lane>>3)&7).
  const int srow = lane >> 3;
  const int schunk = ((lane & 7) ^ ((lane >> 3) & 7)) * 8;  // halfs
  const half_t* gA = At + (size_t)(n0 + w * 32 + srow) * KTOT + k0 + schunk;
  const half_t* gB = Bt + (size_t)(m0 + w * 64 + srow) * KTOT + k0 + schunk;
  half_t* lA = As + (w * 32) * 64;  // wave-uniform LDS bases
  half_t* lB = Bs + (w * 64) * 64;

  const int wm = (w & 1) * 64;    // n-dim wave offset
  const int wn = (w >> 1) * 128;  // m-dim wave offset
  const int fra = wm + (lane & 15);
  const int frb = wn + (lane & 15);
  // frag k-chunk slot per k-half s: ((s*4 + lane>>4) ^ (row&7))*8, row&7 = lane&7
  const int fk0 = (((lane >> 4)    ) ^ (lane & 7)) * 8;
  const int fk1 = ((4 + (lane >> 4)) ^ (lane & 7)) * 8;

  f32x4 acc[4][8] = {};

  for (int kt = 0; kt < 8; ++kt) {
    const half_t* ga = gA + kt * 64;
    const half_t* gb = gB + kt * 64;
#pragma unroll
    for (int i = 0; i < 4; ++i)
      __builtin_amdgcn_global_load_lds((const GLOBAL_AS void*)(ga + (size_t)(i * 8) * KTOT),
                                       (LDS_AS void*)(lA + i * 8 * 64), 16, 0, 0);
#pragma unroll
    for (int i = 0; i < 8; ++i)
      __builtin_amdgcn_global_load_lds((const GLOBAL_AS void*)(gb + (size_t)(i * 8) * KTOT),
                                       (LDS_AS void*)(lB + i * 8 * 64), 16, 0, 0);
    __syncthreads();
#pragma unroll
    for (int s = 0; s < 2; ++s) {
      const int fk = s ? fk1 : fk0;
      f16x8 af[4], bf[8];
#pragma unroll
      for (int i = 0; i < 4; ++i) af[i] = *(const f16x8*)(As + (fra + i * 16) * 64 + fk);
#pragma unroll
      for (int j = 0; j < 8; ++j) bf[j] = *(const f16x8*)(Bs + (frb + j * 16) * 64 + fk);
#pragma unroll
      for (int i = 0; i < 4; ++i)
#pragma unroll
        for (int j = 0; j < 8; ++j)
          acc[i][j] = __builtin_amdgcn_mfma_f32_16x16x32_f16(af[i], bf[j], acc[i][j], 0, 0, 0);
    }
    __syncthreads();
  }

  // masked-sum epilogue; C/D: col = lane&15 (m), row = (lane>>4)*4+reg (n).
  // j spans 128 m -> 4 mask words, read as one aligned uint4.
  float local = 0.f;
  const int mbase = (m0 + wn) >> 5;  // multiple of 4 -> uint4-aligned
  const int mbit = lane & 15;
#pragma unroll
  for (int i = 0; i < 4; ++i) {
    const int ng = n0 + wm + i * 16 + (lane >> 4) * 4;
#pragma unroll
    for (int r = 0; r < 4; ++r) {
      const uint4 wv = *(const uint4*)(maskw + (size_t)(ng + r) * MW + mbase);
      const uint32_t ww[4] = {wv.x, wv.y, wv.z, wv.w};
#pragma unroll
      for (int jp = 0; jp < 4; ++jp) {
        if ((ww[jp] >> mbit) & 1u)        local += acc[i][2 * jp][r];
        if ((ww[jp] >> (mbit + 16)) & 1u) local += acc[i][2 * jp + 1][r];
      }
    }
  }
#pragma unroll
  for (int off = 32; off; off >>= 1) local += __shfl_down(local, off, 64);
  if (lane == 0) red[w] = local;
  __syncthreads();
  if (t == 0) s_part[bi] = red[0] + red[1] + red[2] + red[3];
}

// ------- 3. finalize: reduce 1296 s-partials + 864 count-partials -------
__global__ void finalize_kernel(const float* __restrict__ s_part,
                                const unsigned int* __restrict__ c_part,
                                float* __restrict__ out) {
  const int t = threadIdx.x;
  float local = 0.f;
  for (int i = t; i < 1296; i += 256) local += s_part[i];
  unsigned int clocal = 0;
  for (int i = t; i < 864; i += 256) clocal += c_part[i];
#pragma unroll
  for (int off = 32; off; off >>= 1) {
    local += __shfl_down(local, off, 64);
    clocal += __shfl_down(clocal, off, 64);
  }
  __shared__ float red[4];
  __shared__ unsigned int credu[4];
  if ((t & 63) == 0) { red[t >> 6] = local; credu[t >> 6] = clocal; }
  __syncthreads();
  if (t == 0) {
    const float s = red[0] + red[1] + red[2] + red[3];
    const float cnt = (float)(credu[0] + credu[1] + credu[2] + credu[3]);
    out[0] = -s / (cnt * (float)BATCH);
  }
}

extern "C" void kernel_launch(void* const* d_in, const int* in_sizes, int n_in,
                              void* d_out, int out_size, void* d_ws, size_t ws_size,
                              hipStream_t stream) {
  const float* y    = (const float*)d_in[0];
  const float* yp   = (const float*)d_in[1];
  const float* z    = (const float*)d_in[2];
  const float* zp   = (const float*)d_in[3];
  const float* dist = (const float*)d_in[4];
  float* out = (float*)d_out;

  char* ws = (char*)d_ws;
  float* s_part = (float*)ws;
  unsigned int* c_part = (unsigned int*)(ws + 8192);
  half_t* At = (half_t*)(ws + 16384);
  half_t* Bt = (half_t*)(ws + 16384 + 18874368);
  uint32_t* maskw = (uint32_t*)(ws + 16384 + 2 * 18874368);

  prep_kernel<<<dim3(36, 8, 7), 256, 0, stream>>>(y, yp, z, zp, dist, At, Bt, maskw, c_part);
  gemm_kernel<<<dim3(1296), 256, 0, stream>>>(At, Bt, maskw, s_part);
  finalize_kernel<<<1, 256, 0, stream>>>(s_part, c_part, out);
}